// Round 3
// baseline (1079.199 us; speedup 1.0000x reference)
//
#include <hip/hip_runtime.h>
#include <hip/hip_bf16.h>

// Problem: two MLP heads over gathered rows of per_atom_out [524288, 256].
//  - stem head:  gather n_stems=131072 rows -> 256x256 +b, LeakyReLU, 105x256 +b
//  - bond head:  per-ATOM 256x256 +b, LeakyReLU, dot w_b2 +b  -> scalar per atom;
//                per bond: 0.5*(s[a0]+s[a1])   (algebraically == reference)
//  - per_mol_out passthrough.
// Output layout (flat fp32): [n_stems*105][B][n_bonds]

typedef _Float16 f16;
typedef f16 f16x4 __attribute__((ext_vector_type(4)));
typedef f16 f16x8 __attribute__((ext_vector_type(8)));
typedef float f32x4 __attribute__((ext_vector_type(4)));

#define DIM 256
#define NEG_SLOPE 0.01f

__device__ __forceinline__ float lrelu(float x) { return x >= 0.f ? x : NEG_SLOPE * x; }

// ---------------------------------------------------------------------------
// Bond head, stage 1: per-atom scalar.  GEMM [natoms,256]x[256,256]^T fused with
// LeakyReLU + dot(w_b2) reduction.  BM=128 rows/block, BN=256 (all hidden cols,
// so no atomics), BK=64, 4 waves (each wave owns 64 hidden cols).
// ---------------------------------------------------------------------------
__global__ __launch_bounds__(256, 2)
void bond_atom_kernel(const float* __restrict__ A, const float* __restrict__ w1,
                      const float* __restrict__ b1, const float* __restrict__ w2,
                      const float* __restrict__ b2, float* __restrict__ scal,
                      int natoms)
{
    __shared__ f16 As[128][72];    // 18 KB  (+8 pad: 144B stride, 16B aligned)
    __shared__ f16 Ws[256][72];    // 36 KB
    __shared__ float red[128][4];  // 2 KB

    const int t    = threadIdx.x;
    const int lane = t & 63;
    const int wv   = t >> 6;
    const int row0 = blockIdx.x * 128;

    f32x4 acc[8][4];
#pragma unroll
    for (int m = 0; m < 8; ++m)
#pragma unroll
        for (int n = 0; n < 4; ++n) acc[m][n] = (f32x4){0.f, 0.f, 0.f, 0.f};

    for (int kt = 0; kt < 4; ++kt) {
        // stage A slice 128x64 (fp32 -> f16), fully coalesced
#pragma unroll
        for (int p = 0; p < 8; ++p) {
            int fid = p * 256 + t;
            int r = fid >> 4, c4 = (fid & 15) * 4;
            int gr = row0 + r; if (gr >= natoms) gr = natoms - 1;
            const float4 v = *(const float4*)(&A[(size_t)gr * DIM + kt * 64 + c4]);
            f16x4 h = { (f16)v.x, (f16)v.y, (f16)v.z, (f16)v.w };
            *(f16x4*)(&As[r][c4]) = h;
        }
        // stage W slice 256x64 (L2-resident weight)
#pragma unroll
        for (int p = 0; p < 16; ++p) {
            int fid = p * 256 + t;
            int r = fid >> 4, c4 = (fid & 15) * 4;
            const float4 v = *(const float4*)(&w1[(size_t)r * DIM + kt * 64 + c4]);
            f16x4 h = { (f16)v.x, (f16)v.y, (f16)v.z, (f16)v.w };
            *(f16x4*)(&Ws[r][c4]) = h;
        }
        __syncthreads();
#pragma unroll
        for (int kk = 0; kk < 2; ++kk) {
            f16x8 a[8], b[4];
#pragma unroll
            for (int m = 0; m < 8; ++m)
                a[m] = *(const f16x8*)(&As[m * 16 + (lane & 15)][kk * 32 + (lane >> 4) * 8]);
#pragma unroll
            for (int n = 0; n < 4; ++n)
                b[n] = *(const f16x8*)(&Ws[wv * 64 + n * 16 + (lane & 15)][kk * 32 + (lane >> 4) * 8]);
#pragma unroll
            for (int m = 0; m < 8; ++m)
#pragma unroll
                for (int n = 0; n < 4; ++n)
                    acc[m][n] = __builtin_amdgcn_mfma_f32_16x16x32_f16(a[m], b[n], acc[m][n], 0, 0, 0);
        }
        __syncthreads();
    }

    // epilogue: +b1, LeakyReLU, *w2[col], reduce over cols
    float part[8][4];
#pragma unroll
    for (int m = 0; m < 8; ++m)
#pragma unroll
        for (int r = 0; r < 4; ++r) part[m][r] = 0.f;

#pragma unroll
    for (int n = 0; n < 4; ++n) {
        int col = wv * 64 + n * 16 + (lane & 15);
        float bb = b1[col], ww = w2[col];
#pragma unroll
        for (int m = 0; m < 8; ++m)
#pragma unroll
            for (int r = 0; r < 4; ++r) {
                float v = acc[m][n][r] + bb;
                part[m][r] += lrelu(v) * ww;
            }
    }
    // butterfly over lane&15 (cols), rows live in lane>>4 & reg
#pragma unroll
    for (int m = 0; m < 8; ++m)
#pragma unroll
        for (int r = 0; r < 4; ++r) {
            float s = part[m][r];
            s += __shfl_xor(s, 1, 64);
            s += __shfl_xor(s, 2, 64);
            s += __shfl_xor(s, 4, 64);
            s += __shfl_xor(s, 8, 64);
            if ((lane & 15) == 0) red[m * 16 + (lane >> 4) * 4 + r][wv] = s;
        }
    __syncthreads();
    if (t < 128) {
        int gr = row0 + t;
        if (gr < natoms)
            scal[gr] = red[t][0] + red[t][1] + red[t][2] + red[t][3] + b2[0];
    }
}

// ---------------------------------------------------------------------------
// Stem head: gather 64 rows/block, layer1 (256->256 +b, LeakyReLU) into LDS as
// f16, layer2 (105(->pad112)x256 +b) -> direct store. 4 waves.
// ---------------------------------------------------------------------------
__global__ __launch_bounds__(256, 2)
void stem_kernel(const float* __restrict__ A, const float* __restrict__ w1,
                 const float* __restrict__ b1, const float* __restrict__ w2,
                 const float* __restrict__ b2, const int* __restrict__ slices,
                 const int* __restrict__ stems_batch, const int* __restrict__ stems,
                 float* __restrict__ out, int n_stems, int natoms)
{
    __shared__ f16 H1[64][264];    // 33 KB  (264*2B = 528B stride, 16B aligned)
    __shared__ f16 As[64][72];     // 9 KB
    __shared__ f16 Ws[256][72];    // 36 KB (layer1 W slices; reused for layer2)
    __shared__ int rowsrc[64];

    const int t    = threadIdx.x;
    const int lane = t & 63;
    const int wv   = t >> 6;
    const int s0   = blockIdx.x * 64;

    if (t < 64) {
        int i = s0 + t;
        int rs = 0;
        if (i < n_stems) rs = slices[stems_batch[i]] + stems[i];
        if (rs >= natoms) rs = natoms - 1;
        rowsrc[t] = rs;
    }
    __syncthreads();

    // ---- layer 1 ----
    f32x4 acc1[4][4];
#pragma unroll
    for (int m = 0; m < 4; ++m)
#pragma unroll
        for (int n = 0; n < 4; ++n) acc1[m][n] = (f32x4){0.f, 0.f, 0.f, 0.f};

    for (int kt = 0; kt < 4; ++kt) {
#pragma unroll
        for (int p = 0; p < 4; ++p) {   // A gather: 64x64
            int fid = p * 256 + t;
            int r = fid >> 4, c4 = (fid & 15) * 4;
            const float4 v = *(const float4*)(&A[(size_t)rowsrc[r] * DIM + kt * 64 + c4]);
            f16x4 h = { (f16)v.x, (f16)v.y, (f16)v.z, (f16)v.w };
            *(f16x4*)(&As[r][c4]) = h;
        }
#pragma unroll
        for (int p = 0; p < 16; ++p) {  // W1: 256x64
            int fid = p * 256 + t;
            int r = fid >> 4, c4 = (fid & 15) * 4;
            const float4 v = *(const float4*)(&w1[(size_t)r * DIM + kt * 64 + c4]);
            f16x4 h = { (f16)v.x, (f16)v.y, (f16)v.z, (f16)v.w };
            *(f16x4*)(&Ws[r][c4]) = h;
        }
        __syncthreads();
#pragma unroll
        for (int kk = 0; kk < 2; ++kk) {
            f16x8 a[4], b[4];
#pragma unroll
            for (int m = 0; m < 4; ++m)
                a[m] = *(const f16x8*)(&As[m * 16 + (lane & 15)][kk * 32 + (lane >> 4) * 8]);
#pragma unroll
            for (int n = 0; n < 4; ++n)
                b[n] = *(const f16x8*)(&Ws[wv * 64 + n * 16 + (lane & 15)][kk * 32 + (lane >> 4) * 8]);
#pragma unroll
            for (int m = 0; m < 4; ++m)
#pragma unroll
                for (int n = 0; n < 4; ++n)
                    acc1[m][n] = __builtin_amdgcn_mfma_f32_16x16x32_f16(a[m], b[n], acc1[m][n], 0, 0, 0);
        }
        __syncthreads();
    }
    // layer1 epilogue -> H1 (f16)
#pragma unroll
    for (int n = 0; n < 4; ++n) {
        int col = wv * 64 + n * 16 + (lane & 15);
        float bb = b1[col];
#pragma unroll
        for (int m = 0; m < 4; ++m)
#pragma unroll
            for (int r = 0; r < 4; ++r) {
                float v = acc1[m][n][r] + bb;
                H1[m * 16 + (lane >> 4) * 4 + r][col] = (f16)lrelu(v);
            }
    }
    __syncthreads();

    // ---- layer 2: out 64x112(105), K=256; wave wv owns rows [wv*16, wv*16+16) ----
    f32x4 acc2[7];
#pragma unroll
    for (int n = 0; n < 7; ++n) acc2[n] = (f32x4){0.f, 0.f, 0.f, 0.f};

    for (int kt = 0; kt < 4; ++kt) {
#pragma unroll
        for (int p = 0; p < 7; ++p) {   // W2: 112x64 (rows >=105 zero)
            int fid = p * 256 + t;
            int r = fid >> 4, c4 = (fid & 15) * 4;
            f16x4 h = { (f16)0.f, (f16)0.f, (f16)0.f, (f16)0.f };
            if (r < 105) {
                const float4 v = *(const float4*)(&w2[(size_t)r * DIM + kt * 64 + c4]);
                h = (f16x4){ (f16)v.x, (f16)v.y, (f16)v.z, (f16)v.w };
            }
            *(f16x4*)(&Ws[r][c4]) = h;
        }
        __syncthreads();
#pragma unroll
        for (int kk = 0; kk < 2; ++kk) {
            f16x8 a = *(const f16x8*)(&H1[wv * 16 + (lane & 15)][kt * 64 + kk * 32 + (lane >> 4) * 8]);
#pragma unroll
            for (int n = 0; n < 7; ++n) {
                f16x8 b = *(const f16x8*)(&Ws[n * 16 + (lane & 15)][kk * 32 + (lane >> 4) * 8]);
                acc2[n] = __builtin_amdgcn_mfma_f32_16x16x32_f16(a, b, acc2[n], 0, 0, 0);
            }
        }
        __syncthreads();
    }
    // layer2 epilogue: +b2, store (cols < 105 only)
#pragma unroll
    for (int n = 0; n < 7; ++n) {
        int col = n * 16 + (lane & 15);
        if (col < 105) {
            float bb = b2[col];
#pragma unroll
            for (int r = 0; r < 4; ++r) {
                int row = s0 + wv * 16 + (lane >> 4) * 4 + r;
                if (row < n_stems)
                    out[(size_t)row * 105 + col] = acc2[n][r] + bb;
            }
        }
    }
}

// ---------------------------------------------------------------------------
// Bond combine + per_mol passthrough
// ---------------------------------------------------------------------------
__global__ void combine_kernel(const float* __restrict__ scal, const float* __restrict__ per_mol,
                               const int* __restrict__ slices, const int* __restrict__ bonds,
                               const int* __restrict__ bonds_batch,
                               float* __restrict__ out_mol, float* __restrict__ out_bonds,
                               int n_bonds, int B)
{
    int i = blockIdx.x * 256 + threadIdx.x;
    if (i < n_bonds) {
        int base = slices[bonds_batch[i]];
        float s0 = scal[base + bonds[2 * i]];
        float s1 = scal[base + bonds[2 * i + 1]];
        out_bonds[i] = 0.5f * (s0 + s1);
    }
    if (i < B) out_mol[i] = per_mol[i];
}

extern "C" void kernel_launch(void* const* d_in, const int* in_sizes, int n_in,
                              void* d_out, int out_size, void* d_ws, size_t ws_size,
                              hipStream_t stream) {
    const float* per_atom    = (const float*)d_in[0];
    const float* per_mol     = (const float*)d_in[1];
    const float* w_s1        = (const float*)d_in[2];
    const float* b_s1        = (const float*)d_in[3];
    const float* w_s2        = (const float*)d_in[4];
    const float* b_s2        = (const float*)d_in[5];
    const float* w_b1        = (const float*)d_in[6];
    const float* b_b1        = (const float*)d_in[7];
    const float* w_b2        = (const float*)d_in[8];
    const float* b_b2        = (const float*)d_in[9];
    const int*   slices      = (const int*)d_in[10];
    const int*   stems_batch = (const int*)d_in[11];
    const int*   stems       = (const int*)d_in[12];
    const int*   bonds       = (const int*)d_in[13];
    const int*   bonds_batch = (const int*)d_in[14];

    const int natoms  = in_sizes[0] / DIM;
    const int B       = in_sizes[1];
    const int n_stems = in_sizes[11];
    const int n_bonds = in_sizes[14];

    float* out      = (float*)d_out;
    float* out_stem = out;
    float* out_mol  = out + (size_t)n_stems * 105;
    float* out_bond = out_mol + B;
    float* scal     = (float*)d_ws;   // natoms floats (written before read)

    bond_atom_kernel<<<(natoms + 127) / 128, 256, 0, stream>>>(
        per_atom, w_b1, b_b1, w_b2, b_b2, scal, natoms);
    stem_kernel<<<(n_stems + 63) / 64, 256, 0, stream>>>(
        per_atom, w_s1, b_s1, w_s2, b_s2, slices, stems_batch, stems,
        out_stem, n_stems, natoms);
    const int ncomb = (n_bonds > B ? n_bonds : B);
    combine_kernel<<<(ncomb + 255) / 256, 256, 0, stream>>>(
        scal, per_mol, slices, bonds, bonds_batch, out_mol, out_bond, n_bonds, B);
}